// Round 11
// baseline (248.662 us; speedup 1.0000x reference)
//
#include <hip/hip_runtime.h>
#include <math.h>

#define HW 65536
#define DD 160
#define NB 2
#define DCH 40
#define NSL (DCH + 6)   // 46 marched slices per chunk incl. halo
#define NCH 4
#define TW 32
#define TH 16
#define PH 23           // h-pitch in f32x2 units (odd -> 2-way LDS, free)

#define SSIM_C1 1e-4f
#define SSIM_C2 9e-4f

typedef float f32x2 __attribute__((ext_vector_type(2)));
typedef float f32x4 __attribute__((ext_vector_type(4)));

struct Gw { float g[7]; };

static __device__ __forceinline__ f32x2 s2(float v) { f32x2 r; r.x = v; r.y = v; return r; }

// Fused SSIM3D v11: R7 structure (best: double-buffered transposed planes,
// one barrier/slice, DCH=40, 1024 blocks) with the u/v 4-field algebra
// (u=x+y, v=x-v -> conv fields {u,v,u^2,v^2}) applied AT CONSUMPTION.
// LOAD is byte-identical to R7: raw x,y into cxy, no load-dependent math
// at the issue site, so the vmcnt wait sinks to next-iteration use.
__global__ __launch_bounds__(256, 2) void k_fused(
    const float* __restrict__ img1, const float* __restrict__ img2,
    Gw gw, float* __restrict__ partials)
{
    __shared__ f32x2 pUV[2][TW][PH];   // (conv_w u, conv_w v)
    __shared__ f32x2 pSQ[2][TW][PH];   // (conv_w u^2, conv_w v^2)
    __shared__ float red[256];

    const int tid = threadIdx.x;
    const int nb = blockIdx.z >> 2;
    const int o0 = (blockIdx.z & 3) * DCH;
    const int h0 = blockIdx.y * TH;
    const int w0 = blockIdx.x * TW;
    const float* i1 = img1 + (size_t)nb * DD * HW;
    const float* i2 = img2 + (size_t)nb * DD * HW;
    const bool fastb = (blockIdx.x >= 1) && (blockIdx.x <= 6) &&
                       (blockIdx.y >= 1) && (blockIdx.y <= 14);

    // ---- W-thread geometry (tid < 176): row hh (0..21), 4 outputs at wb ----
    const bool wth = (tid < 176);
    const int hh = tid >> 3;
    const int wb = (tid & 7) * 4;
    const int gh = h0 - 3 + hh;
    const int gwb = w0 - 3 + wb;       // == 1 (mod 4)
    const bool ghv = wth && ((unsigned)gh < 256u);
    const int ghc = gh < 0 ? 0 : (gh > 255 ? 255 : gh);
    const int gbase = gh * 256 + (gwb - 1);   // 16B-aligned (fast path only)
    int coff[10];
    unsigned wbits = 0;
#pragma unroll
    for (int i = 0; i < 10; ++i) {
        int gwi = gwb + i;
        int gc = gwi < 0 ? 0 : (gwi > 255 ? 255 : gwi);
        coff[i] = ghc * 256 + gc;                 // always-in-bounds address
        if (ghv && gwi == gc) wbits |= (1u << i); // zero-pad mask bit
    }

    // ---- H/D geometry: all 256 threads, 2 output rows each ----
    const int wcol = tid & 31;
    const int hb = (tid >> 5) * 2;   // 0..14

    f32x2 ringUV[2][7] = {};
    f32x2 ringSQ[2][7] = {};
    float lsum = 0.f;
    f32x2 cxy[10];   // raw (x, y) per window pixel — NO math at load site

    // slice loader: byte-identical behavior to R7 (raw values, zero-padded)
    auto LOAD = [&](int s) {
        const float* p1 = i1 + (size_t)s * HW;
        const float* p2 = i2 + (size_t)s * HW;
        if (fastb) {
            const f32x4 a0 = *(const f32x4*)(p1 + gbase);
            const f32x4 a1 = *(const f32x4*)(p1 + gbase + 4);
            const f32x4 a2 = *(const f32x4*)(p1 + gbase + 8);
            const f32x4 b0 = *(const f32x4*)(p2 + gbase);
            const f32x4 b1 = *(const f32x4*)(p2 + gbase + 4);
            const f32x4 b2 = *(const f32x4*)(p2 + gbase + 8);
            cxy[0].x = a0.y; cxy[1].x = a0.z; cxy[2].x = a0.w; cxy[3].x = a1.x;
            cxy[4].x = a1.y; cxy[5].x = a1.z; cxy[6].x = a1.w; cxy[7].x = a2.x;
            cxy[8].x = a2.y; cxy[9].x = a2.z;
            cxy[0].y = b0.y; cxy[1].y = b0.z; cxy[2].y = b0.w; cxy[3].y = b1.x;
            cxy[4].y = b1.y; cxy[5].y = b1.z; cxy[6].y = b1.w; cxy[7].y = b2.x;
            cxy[8].y = b2.y; cxy[9].y = b2.z;
        } else {
#pragma unroll
            for (int i = 0; i < 10; ++i) {
                const float vx = p1[coff[i]];
                const float vy = p2[coff[i]];
                const bool ok = (wbits >> i) & 1u;
                cxy[i].x = ok ? vx : 0.f;
                cxy[i].y = ok ? vy : 0.f;
            }
        }
    };

    // prologue: load slice r=0 (s = o0-3)
    {
        const int s0 = o0 - 3;
        if (s0 >= 0 && wth) LOAD(s0);
    }

    for (int t = 0; t < 7; ++t) {
#pragma unroll
        for (int p = 0; p < 7; ++p) {
            const int r = 7 * t + p;
            if (r <= NSL) {
                const int scur = o0 - 3 + r;
                const bool wv = (r < NSL) && (scur >= 0) && (scur < DD);
                const int snx = scur + 1;
                const bool pfv = (r + 1 < NSL) && (snx >= 0) && (snx < DD);

                // 1) W-pass: u/v transform HERE (one phase after load issue)
                if (wv && wth) {
                    f32x2 aUV[4] = {};
                    f32x2 aSQ[4] = {};
#pragma unroll
                    for (int i = 0; i < 10; ++i) {
                        f32x2 uv;
                        uv.x = cxy[i].x + cxy[i].y;
                        uv.y = cxy[i].x - cxy[i].y;
                        const f32x2 sq = uv * uv;         // v_pk_mul_f32
#pragma unroll
                        for (int o = 0; o < 4; ++o) {
                            const int k = i - o;
                            if (k >= 0 && k < 7) {
                                const float gk = gw.g[k];
                                aUV[o] += s2(gk) * uv;    // v_pk_fma_f32
                                aSQ[o] += s2(gk) * sq;
                            }
                        }
                    }
                    const int buf = r & 1;
#pragma unroll
                    for (int o = 0; o < 4; ++o) {
                        pUV[buf][wb + o][hh] = aUV[o];
                        pSQ[buf][wb + o][hh] = aSQ[o];
                    }
                }

                // 2) prefetch next slice into cxy (raw; consumed next iteration)
                if (pfv && wth) LOAD(snx);

                // 3) H-pass + D-ring + SSIM for slice rp = r-1 (other buffer)
                if (r >= 1) {
                    const int rp = r - 1;
                    const int sp = o0 - 3 + rp;
                    const int pi = (p + 6) % 7;   // == rp % 7, compile-time
                    if (sp >= 0 && sp < DD) {
                        const int buf = rp & 1;
                        f32x2 vU[8], vS[8];
#pragma unroll
                        for (int i = 0; i < 8; ++i) {
                            vU[i] = pUV[buf][wcol][hb + i];
                            vS[i] = pSQ[buf][wcol][hb + i];
                        }
#pragma unroll
                        for (int o = 0; o < 2; ++o) {
                            f32x2 aU = s2(0.f), aS = s2(0.f);
#pragma unroll
                            for (int k = 0; k < 7; ++k) {
                                const float gk = gw.g[k];
                                aU += s2(gk) * vU[o + k];
                                aS += s2(gk) * vS[o + k];
                            }
                            ringUV[o][pi] = aU;
                            ringSQ[o][pi] = aS;
                        }
                    } else {
#pragma unroll
                        for (int o = 0; o < 2; ++o) {
                            ringUV[o][pi] = s2(0.f);
                            ringSQ[o][pi] = s2(0.f);
                        }
                    }
                    if (r >= 7) {
#pragma unroll
                        for (int o = 0; o < 2; ++o) {
                            f32x2 cU = s2(0.f), cS = s2(0.f);
#pragma unroll
                            for (int k = 0; k < 7; ++k) {
                                const float gk = gw.g[k];
                                const int pp = (pi + 1 + k) % 7;
                                cU += s2(gk) * ringUV[o][pp];
                                cS += s2(gk) * ringSQ[o][pp];
                            }
                            // A=conv(u), B=conv(v), P=conv(u^2), Q=conv(v^2)
                            const f32x2 ab2 = cU * cU;          // (A^2, B^2)
                            const float sAB = ab2.x + ab2.y;
                            const float dAB = ab2.x - ab2.y;
                            const float sPQ = cS.x + cS.y;
                            const float dPQ = cS.x - cS.y;
                            const float num1 = 0.5f * dAB + SSIM_C1;          // 2*mu1*mu2+C1
                            const float num2 = 0.5f * (dPQ - dAB) + SSIM_C2;  // 2*sig12+C2
                            const float den1 = 0.5f * sAB + SSIM_C1;          // mu1^2+mu2^2+C1
                            const float den2 = 0.5f * (sPQ - sAB) + SSIM_C2;  // sig1+sig2+C2
                            lsum += (num1 * num2) * __builtin_amdgcn_rcpf(den1 * den2);
                        }
                    }
                }
                __syncthreads();
            }
        }
    }

    // deterministic block reduction
    red[tid] = lsum;
    __syncthreads();
    for (int off = 128; off > 0; off >>= 1) {
        if (tid < off) red[tid] += red[tid + off];
        __syncthreads();
    }
    if (tid == 0)
        partials[(blockIdx.z * gridDim.y + blockIdx.y) * gridDim.x + blockIdx.x] = red[0];
}

__global__ __launch_bounds__(256) void k_final(
    const float* __restrict__ partials, int n, float scale, float* __restrict__ out)
{
    __shared__ float red[256];
    float s = 0.f;
    for (int i = threadIdx.x; i < n; i += 256) s += partials[i];
    red[threadIdx.x] = s;
    __syncthreads();
    for (int off = 128; off > 0; off >>= 1) {
        if (threadIdx.x < off) red[threadIdx.x] += red[threadIdx.x + off];
        __syncthreads();
    }
    if (threadIdx.x == 0) out[0] = red[0] * scale;
}

extern "C" void kernel_launch(void* const* d_in, const int* in_sizes, int n_in,
                              void* d_out, int out_size, void* d_ws, size_t ws_size,
                              hipStream_t stream)
{
    const float* img1 = (const float*)d_in[0];
    const float* img2 = (const float*)d_in[1];
    float* out = (float*)d_out;
    float* partials = (float*)d_ws;

    Gw gw;
    {
        double gs[7], sum = 0.0;
        for (int i = 0; i < 7; ++i) { double x = i - 3; gs[i] = exp(-x * x / 4.5); sum += gs[i]; }
        for (int i = 0; i < 7; ++i) gw.g[i] = (float)(gs[i] / sum);
    }

    dim3 grid(256 / TW, 256 / TH, NB * NCH);   // 8 x 16 x 8 = 1024 blocks
    k_fused<<<grid, dim3(256), 0, stream>>>(img1, img2, gw, partials);
    k_final<<<dim3(1), dim3(256), 0, stream>>>(
        partials, (256 / TW) * (256 / TH) * NB * NCH, (float)(1.0 / 20971520.0), out);
}